// Round 16
// baseline (384.258 us; speedup 1.0000x reference)
//
#include <hip/hip_runtime.h>
#include <hip/hip_bf16.h>

#define N_NODES 50000
#define E_EDGES 800000

using u16 = unsigned short;
typedef short bf8 __attribute__((ext_vector_type(8)));
typedef float f32x4 __attribute__((ext_vector_type(4)));

__device__ __forceinline__ float bf2f(u16 h) {
    union { unsigned u; float f; } v;
    v.u = ((unsigned)h) << 16;
    return v.f;
}
__device__ __forceinline__ u16 f2bf(float f) {
    union { float f; unsigned u; } v;
    v.f = f;
    unsigned r = v.u + 0x7FFF + ((v.u >> 16) & 1);
    return (u16)(r >> 16);
}

#define GLOAD_LDS16(gsrc, ldst)                                            \
    __builtin_amdgcn_global_load_lds(                                      \
        (const __attribute__((address_space(1))) void*)(gsrc),             \
        (__attribute__((address_space(3))) void*)(ldst), 16, 0, 0)

// ---------------- weight pack: W[k][n] fp32 -> MFMA B-fragment order bf16 ----
struct WtArgs {
    const float* src[9];
    u16* dst[9];
    int K[9];
    int N[9];
};

__global__ __launch_bounds__(256) void k_wpack(WtArgs a) {
    int wi = blockIdx.y;
    int K = a.K[wi], NC = a.N[wi];
    int KS = K / 32;
    int chunks = (NC / 16) * KS * 64;
    for (int c = blockIdx.x * 256 + threadIdx.x; c < chunks;
         c += gridDim.x * 256) {
        int l = c & 63;
        int rest = c >> 6;  // gni*KS + ks
        int ks = rest % KS, gni = rest / KS;
        int n = gni * 16 + (l & 15);
        int kb = ks * 32 + (l >> 4) * 8;
        u16 outv[8];
#pragma unroll
        for (int j = 0; j < 8; ++j)
            outv[j] = f2bf(a.src[wi][(size_t)(kb + j) * NC + n]);
        *(bf8*)&a.dst[wi][(size_t)c * 8] = *(bf8*)outv;
    }
}

// ---------------- prep: h0 = x/1000 - 0.5, fp32 -> bf16 ----------------
__global__ __launch_bounds__(256) void k_prep(const float* __restrict__ x,
                                              u16* __restrict__ h0) {
    int total = N_NODES * 128 / 4;
    for (int i = blockIdx.x * 256 + threadIdx.x; i < total;
         i += gridDim.x * 256) {
        float4 v = *(const float4*)(x + (size_t)i * 4);
        ushort4 o;
        o.x = f2bf(v.x * 0.001f - 0.5f);
        o.y = f2bf(v.y * 0.001f - 0.5f);
        o.z = f2bf(v.z * 0.001f - 0.5f);
        o.w = f2bf(v.w * 0.001f - 0.5f);
        *(ushort4*)(h0 + (size_t)i * 4) = o;
    }
}

// ---------------- degree count ----------------
__global__ void k_count(const int* __restrict__ dst, int* __restrict__ deg) {
    for (int i = blockIdx.x * blockDim.x + threadIdx.x; i < E_EDGES;
         i += gridDim.x * blockDim.x)
        atomicAdd(&deg[dst[i]], 1);
}

// ---------------- 3-phase parallel exclusive scan ----------------
#define SCAN_B 49  // ceil(50000/1024)

__global__ __launch_bounds__(1024) void k_scan1(const int* __restrict__ deg,
                                                int* __restrict__ bsum) {
    __shared__ int sm[1024];
    int i = blockIdx.x * 1024 + threadIdx.x;
    sm[threadIdx.x] = (i < N_NODES) ? deg[i] : 0;
    __syncthreads();
    for (int ofs = 512; ofs > 0; ofs >>= 1) {
        if (threadIdx.x < ofs) sm[threadIdx.x] += sm[threadIdx.x + ofs];
        __syncthreads();
    }
    if (threadIdx.x == 0) bsum[blockIdx.x] = sm[0];
}

__global__ void k_scan2(const int* __restrict__ bsum, int* __restrict__ bofs) {
    int l = threadIdx.x;  // one wave of 64
    int v = (l < SCAN_B) ? bsum[l] : 0;
    int orig = v;
    for (int d = 1; d < 64; d <<= 1) {
        int u = __shfl_up(v, d, 64);
        if (l >= d) v += u;
    }
    if (l < SCAN_B) bofs[l] = v - orig;  // exclusive
}

__global__ __launch_bounds__(1024) void k_scan3(const int* __restrict__ deg,
                                                const int* __restrict__ bofs,
                                                int* __restrict__ rowptr,
                                                float* __restrict__ dinv) {
    __shared__ int sm[1024];
    int i = blockIdx.x * 1024 + threadIdx.x;
    int d = (i < N_NODES) ? deg[i] : 0;
    sm[threadIdx.x] = d;
    __syncthreads();
    for (int ofs = 1; ofs < 1024; ofs <<= 1) {
        int u = (threadIdx.x >= (unsigned)ofs) ? sm[threadIdx.x - ofs] : 0;
        __syncthreads();
        sm[threadIdx.x] += u;
        __syncthreads();
    }
    if (i < N_NODES) {
        int incl = sm[threadIdx.x] + bofs[blockIdx.x];
        rowptr[i] = incl - d;
        dinv[i] = 1.0f / fmaxf((float)d, 1.0f);
        if (i == N_NODES - 1) rowptr[N_NODES] = incl;
    }
}

// ---------------- CSR fill ----------------
__global__ void k_fill(const int* __restrict__ src, const int* __restrict__ dst,
                       const int* __restrict__ rowptr, int* __restrict__ cursor,
                       int* __restrict__ colidx) {
    for (int i = blockIdx.x * blockDim.x + threadIdx.x; i < E_EDGES;
         i += gridDim.x * blockDim.x) {
        int d = dst[i];
        int pos = rowptr[d] + atomicAdd(&cursor[d], 1);
        colidx[pos] = src[i];
    }
}

// ---------------- conv phase A: role-split {aggregate | self-GEMM} ----------
// Blocks with bid%R==R-1 compute S = H @ Wp (single-pass MFMA GEMM, packed W
// via global_load_lds, no bias/act, bf16 out). Other blocks run the CSR
// neighbor-mean aggregate (1 wave/node, 16 lanes/edge, x2 unroll). Interleave
// keeps both roles co-resident per CU: the latency-bound gather and the
// MFMA-bound GEMM co-schedule (separate pipes), hiding the self-GEMM time.
template <int K, int NCB, int NC, int YS, int R>
__global__ __launch_bounds__(512) void k_conv_a(
    const u16* __restrict__ H, const u16* __restrict__ Wp,
    const int* __restrict__ rowptr, const int* __restrict__ colidx,
    const float* __restrict__ dinv, u16* __restrict__ meanOut,
    u16* __restrict__ S) {
    constexpr int M = N_NODES;
    constexpr int NG = NCB / 16;
    constexpr int KS = K / 32;
    constexpr int CH = NG * KS * 64;
    constexpr int GX = (M / 16 + 7) / 8;  // 391
    constexpr int GEMM_B = ((GX * YS + 7) / 8) * 8;
    constexpr int CPX = GEMM_B / 8;
    extern __shared__ char smem[];
    u16* Bs = (u16*)smem;

    const int bid = blockIdx.x;
    const int t = threadIdx.x;
    const int lane = t & 63;
    const int wave = t >> 6;
    const int lr = lane & 15;
    const int sub = lane >> 4;

    if (bid % R == R - 1) {
        // ------------- self-GEMM role -------------
        const int gid = bid / R;
        const int wid = (gid & 7) * CPX + (gid >> 3);  // XCD chunking
        const int x = wid / YS;
        const int y = wid % YS;
        if (x >= GX) return;
        const int row0 = (x * 8 + wave) * 16;
        const int arow = row0 + lr;
        const bool rowOK = arow < M;

#pragma unroll
        for (int i = 0; i < CH / 512; ++i) {
            int c = t + i * 512;
            int ks = (c >> 6) % KS;
            int ni = c / (64 * KS);
            const u16* gsrc =
                Wp + (((size_t)(y * NG + ni) * KS + ks) * 64 + lane) * 8;
            u16* ldst = Bs + ((size_t)(i * 512 + wave * 64)) * 8;
            GLOAD_LDS16(gsrc, ldst);
        }

        f32x4 acc[NG];
#pragma unroll
        for (int i = 0; i < NG; ++i) acc[i] = (f32x4){0.f, 0.f, 0.f, 0.f};

        const u16* ap = H + (size_t)arow * K + sub * 8;
        __syncthreads();  // drains vmcnt: W tile landed

        bf8 acur = {0, 0, 0, 0, 0, 0, 0, 0};
        if (rowOK) acur = *(const bf8*)ap;
#pragma unroll
        for (int ks = 0; ks < KS; ++ks) {
            bf8 anext = {0, 0, 0, 0, 0, 0, 0, 0};
            if (ks + 1 < KS && rowOK) anext = *(const bf8*)(ap + (ks + 1) * 32);
#pragma unroll
            for (int ni = 0; ni < NG; ++ni) {
                bf8 b =
                    *(const bf8*)&Bs[(((size_t)ni * KS + ks) * 64 + lane) * 8];
                acc[ni] = __builtin_amdgcn_mfma_f32_16x16x32_bf16(acur, b,
                                                                  acc[ni], 0, 0, 0);
            }
            acur = anext;
        }

#pragma unroll
        for (int ni = 0; ni < NG; ++ni) {
            int col = y * NCB + ni * 16 + lr;
#pragma unroll
            for (int r = 0; r < 4; ++r) {
                int row = row0 + sub * 4 + r;
                if (row >= M) continue;
                S[(size_t)row * NC + col] = f2bf(acc[ni][r]);
            }
        }
        return;
    }

    // ------------- aggregate role -------------
    constexpr int VA = K / 16;  // bf16 per lane (8 or 16)
    const int agg_id = bid - bid / R;
    const int node = agg_id * 8 + wave;
    if (node >= M) return;
    int beg = rowptr[node], end = rowptr[node + 1];
    float acc[VA] = {};
    int e = beg + sub;
    for (; e + 4 < end; e += 8) {
        int s0 = colidx[e];
        int s1 = colidx[e + 4];
        const u16* p0 = H + (size_t)s0 * K + lr * VA;
        const u16* p1 = H + (size_t)s1 * K + lr * VA;
        bf8 r0 = *(const bf8*)p0;
        bf8 r1 = *(const bf8*)p1;
        if (VA == 16) {
            bf8 r0b = *(const bf8*)(p0 + 8);
            bf8 r1b = *(const bf8*)(p1 + 8);
#pragma unroll
            for (int j = 0; j < 8; ++j) {
                acc[j] += bf2f((u16)r0[j]) + bf2f((u16)r1[j]);
                acc[8 + j] += bf2f((u16)r0b[j]) + bf2f((u16)r1b[j]);
            }
        } else {
#pragma unroll
            for (int j = 0; j < 8; ++j)
                acc[j] += bf2f((u16)r0[j]) + bf2f((u16)r1[j]);
        }
    }
    for (; e < end; e += 4) {
        int s = colidx[e];
        const u16* row = H + (size_t)s * K + lr * VA;
        bf8 r0 = *(const bf8*)row;
#pragma unroll
        for (int j = 0; j < 8; ++j) acc[j] += bf2f((u16)r0[j]);
        if (VA == 16) {
            bf8 r1 = *(const bf8*)(row + 8);
#pragma unroll
            for (int j = 0; j < 8; ++j) acc[8 + j] += bf2f((u16)r1[j]);
        }
    }
#pragma unroll
    for (int j = 0; j < VA; ++j) {
        acc[j] += __shfl_xor(acc[j], 16);
        acc[j] += __shfl_xor(acc[j], 32);
    }
    if (sub == 0) {
        float inv = dinv[node];
        u16 outv[VA];
#pragma unroll
        for (int j = 0; j < VA; ++j) outv[j] = f2bf(acc[j] * inv);
        u16* o = meanOut + (size_t)node * K + lr * VA;
        *(bf8*)o = *(bf8*)&outv[0];
        if (VA == 16) *(bf8*)(o + 8) = *(bf8*)&outv[8];
    }
}

// ---------------- conv phase B: mean-GEMM + S + bias + activation -----------
// C = act(mean @ Wp + S + bias). Single-pass, W via global_load_lds, rolling
// A prefetch, XCD-chunked. VAE epilogue fuses the reparameterization.
enum { ACT_NONE = 0, ACT_SIN = 1, ACT_RELU = 2, ACT_SIGMOID1000 = 3, ACT_VAE = 4 };

template <int K, int NCB, int NC, int YS, int ACT, bool OUT_F32, bool ADD_S>
__global__ __launch_bounds__(512) void k_conv_b(
    const u16* __restrict__ A, const u16* __restrict__ Wp,
    const u16* __restrict__ S, const float* __restrict__ bias,
    void* __restrict__ Cout, float* __restrict__ out_mean,
    float* __restrict__ out_lv, const float* __restrict__ eps) {
    constexpr int M = N_NODES;
    constexpr int NG = NCB / 16;
    constexpr int KS = K / 32;
    constexpr int CH = NG * KS * 64;
    constexpr int GX = (M / 16 + 7) / 8;  // 391
    constexpr int GEMM_B = ((GX * YS + 7) / 8) * 8;
    constexpr int CPX = GEMM_B / 8;
    extern __shared__ char smem[];
    u16* Bs = (u16*)smem;

    const int bid = blockIdx.x;
    const int wid = (bid & 7) * CPX + (bid >> 3);  // XCD chunking
    const int x = wid / YS;
    const int y = wid % YS;
    if (x >= GX) return;

    const int t = threadIdx.x;
    const int lane = t & 63;
    const int wave = t >> 6;
    const int lr = lane & 15;
    const int sub = lane >> 4;
    const int row0 = (x * 8 + wave) * 16;
    const int arow = row0 + lr;
    const bool rowOK = arow < M;

    auto mapGroup = [&](int ni) {
        if (ACT == ACT_VAE)
            return ni < NG / 2 ? y * (NG / 2) + ni
                               : (NC / 32) + y * (NG / 2) + (ni - NG / 2);
        return y * NG + ni;
    };

#pragma unroll
    for (int i = 0; i < CH / 512; ++i) {
        int c = t + i * 512;
        int ks = (c >> 6) % KS;
        int ni = c / (64 * KS);
        const u16* gsrc =
            Wp + (((size_t)mapGroup(ni) * KS + ks) * 64 + lane) * 8;
        u16* ldst = Bs + ((size_t)(i * 512 + wave * 64)) * 8;
        GLOAD_LDS16(gsrc, ldst);
    }

    f32x4 acc[NG];
#pragma unroll
    for (int i = 0; i < NG; ++i) acc[i] = (f32x4){0.f, 0.f, 0.f, 0.f};

    const u16* ap = A + (size_t)arow * K + sub * 8;
    __syncthreads();  // drains vmcnt: W tile landed

    bf8 acur = {0, 0, 0, 0, 0, 0, 0, 0};
    if (rowOK) acur = *(const bf8*)ap;
#pragma unroll
    for (int ks = 0; ks < KS; ++ks) {
        bf8 anext = {0, 0, 0, 0, 0, 0, 0, 0};
        if (ks + 1 < KS && rowOK) anext = *(const bf8*)(ap + (ks + 1) * 32);
#pragma unroll
        for (int ni = 0; ni < NG; ++ni) {
            bf8 b = *(const bf8*)&Bs[(((size_t)ni * KS + ks) * 64 + lane) * 8];
            acc[ni] =
                __builtin_amdgcn_mfma_f32_16x16x32_bf16(acur, b, acc[ni], 0, 0, 0);
        }
        acur = anext;
    }

    if (ACT == ACT_VAE) {
        // ni < NG/2 = mean cols, ni+NG/2 = matching log_var cols (+128)
#pragma unroll
        for (int ni = 0; ni < NG / 2; ++ni) {
            int colm = y * (NCB / 2) + ni * 16 + lr;
            float bm = bias[colm];
            float bl = bias[colm + 128];
#pragma unroll
            for (int r = 0; r < 4; ++r) {
                int row = row0 + sub * 4 + r;
                if (row >= M) continue;
                float mv = acc[ni][r] + bm + bf2f(S[(size_t)row * NC + colm]);
                float lv = acc[ni + NG / 2][r] + bl +
                           bf2f(S[(size_t)row * NC + colm + 128]);
                size_t o = (size_t)row * 128 + colm;
                out_mean[o] = mv;
                out_lv[o] = lv;
                ((u16*)Cout)[o] = f2bf(mv + __expf(lv) * eps[o]);
            }
        }
    } else {
#pragma unroll
        for (int ni = 0; ni < NG; ++ni) {
            int col = y * NCB + ni * 16 + lr;
            float bv = bias[col];
#pragma unroll
            for (int r = 0; r < 4; ++r) {
                int row = row0 + sub * 4 + r;
                if (row >= M) continue;
                float v = acc[ni][r] + bv;
                if (ADD_S) v += bf2f(S[(size_t)row * NC + col]);
                if (ACT == ACT_SIN) v = __sinf(v);
                else if (ACT == ACT_RELU) v = fmaxf(v, 0.f);
                else if (ACT == ACT_SIGMOID1000) v = 1000.f / (1.f + __expf(-v));
                if (OUT_F32)
                    ((float*)Cout)[(size_t)row * NC + col] = v;
                else
                    ((u16*)Cout)[(size_t)row * NC + col] = f2bf(v);
            }
        }
    }
}

extern "C" void kernel_launch(void* const* d_in, const int* in_sizes, int n_in,
                              void* d_out, int out_size, void* d_ws,
                              size_t ws_size, hipStream_t stream) {
    const int N = N_NODES;
    const float* x = (const float*)d_in[0];
    const int* ei = (const int*)d_in[1];
    const float* eps = (const float*)d_in[2];
    const float* Wl1 = (const float*)d_in[3];
    const float* bl1 = (const float*)d_in[4];
    const float* Wr1 = (const float*)d_in[5];
    const float* Wl2 = (const float*)d_in[6];
    const float* bl2 = (const float*)d_in[7];
    const float* Wr2 = (const float*)d_in[8];
    const float* Wl3 = (const float*)d_in[9];
    const float* bl3 = (const float*)d_in[10];
    const float* Wr3 = (const float*)d_in[11];
    const float* Wl4 = (const float*)d_in[12];
    const float* bl4 = (const float*)d_in[13];
    const float* Wr4 = (const float*)d_in[14];
    const float* W_lin = (const float*)d_in[15];
    const float* b_lin = (const float*)d_in[16];

    const int* src = ei;
    const int* dst = ei + E_EDGES;

    char* w = (char*)d_ws;
    auto alloc = [&](size_t b) {
        void* p = (void*)w;
        w += (b + 255) & ~(size_t)255;
        return p;
    };
    int* deg = (int*)alloc((size_t)N * 4);
    int* rowptr = (int*)alloc((size_t)(N + 1) * 4);
    int* cursor = (int*)alloc((size_t)N * 4);
    int* colidx = (int*)alloc((size_t)E_EDGES * 4);
    float* dinv = (float*)alloc((size_t)N * 4);
    int* bsum = (int*)alloc(64 * 4);
    int* bofs = (int*)alloc(64 * 4);
    u16* hbA = (u16*)alloc((size_t)N * 256 * 2);
    u16* hbB = (u16*)alloc((size_t)N * 256 * 2);
    u16* hbC = (u16*)alloc((size_t)N * 256 * 2);
    u16* hbS = (u16*)alloc((size_t)N * 256 * 2);
    static const int wK[9] = {128, 128, 256, 256, 128, 128, 128, 128, 128};
    static const int wN[9] = {256, 256, 256, 256, 128, 128, 128, 128, 64};
    u16* Wt[9];
    for (int i = 0; i < 9; ++i) Wt[i] = (u16*)alloc((size_t)wK[i] * wN[i] * 2);

    float* out_final = (float*)d_out;              // N x 64
    float* out_mean = out_final + (size_t)N * 64;  // N x 128
    float* out_lv = out_mean + (size_t)N * 128;    // N x 128

    hipMemsetAsync(deg, 0, (size_t)N * 4, stream);
    hipMemsetAsync(cursor, 0, (size_t)N * 4, stream);

    WtArgs wa;
    const float* wsrc[9] = {Wl1, Wr1, Wl2, Wr2, Wl3, Wr3, Wl4, Wr4, W_lin};
    for (int i = 0; i < 9; ++i) {
        wa.src[i] = wsrc[i];
        wa.dst[i] = Wt[i];
        wa.K[i] = wK[i];
        wa.N[i] = wN[i];
    }
    k_wpack<<<dim3(32, 9), 256, 0, stream>>>(wa);

    k_prep<<<2048, 256, 0, stream>>>(x, hbA);
    k_count<<<3125, 256, 0, stream>>>(dst, deg);
    k_scan1<<<SCAN_B, 1024, 0, stream>>>(deg, bsum);
    k_scan2<<<1, 64, 0, stream>>>(bsum, bofs);
    k_scan3<<<SCAN_B, 1024, 0, stream>>>(deg, bofs, rowptr, dinv);
    k_fill<<<3125, 256, 0, stream>>>(src, dst, rowptr, cursor, colidx);

    // GEMM_B: YS=4 -> 1568, YS=2 -> 784.  R: agg slots = GEMM_B*(R-1) >= 6250.
    auto shm = [](int NCB, int K) { return (size_t)NCB * K * 2; };

    // ---- conv1: h1 = sin(mean(h0)@Wl1 + bl1 + h0@Wr1) -> hbC ----
    k_conv_a<128, 64, 256, 4, 5><<<1568 * 5, 512, shm(64, 128), stream>>>(
        hbA, Wt[1], rowptr, colidx, dinv, hbB, hbS);
    k_conv_b<128, 64, 256, 4, ACT_SIN, false, true>
        <<<1568, 512, shm(64, 128), stream>>>(hbB, Wt[0], hbS, bl1, hbC,
                                              nullptr, nullptr, nullptr);

    // ---- conv2 + fused reparam: out_mean, out_lv, z -> hbA ----
    k_conv_a<256, 64, 256, 4, 5><<<1568 * 5, 512, shm(64, 256), stream>>>(
        hbC, Wt[3], rowptr, colidx, dinv, hbB, hbS);
    k_conv_b<256, 64, 256, 4, ACT_VAE, false, true>
        <<<1568, 512, shm(64, 256), stream>>>(hbB, Wt[2], hbS, bl2, hbA,
                                              out_mean, out_lv, eps);

    // ---- conv3: h3 = relu(mean(z)@Wl3 + bl3 + z@Wr3) -> hbC ----
    k_conv_a<128, 64, 128, 2, 9><<<784 * 9, 512, shm(64, 128), stream>>>(
        hbA, Wt[5], rowptr, colidx, dinv, hbB, hbS);
    k_conv_b<128, 64, 128, 2, ACT_RELU, false, true>
        <<<784, 512, shm(64, 128), stream>>>(hbB, Wt[4], hbS, bl3, hbC,
                                             nullptr, nullptr, nullptr);

    // ---- conv4: h4 = relu(mean(h3)@Wl4 + bl4 + h3@Wr4) -> hbA ----
    k_conv_a<128, 64, 128, 2, 9><<<784 * 9, 512, shm(64, 128), stream>>>(
        hbC, Wt[7], rowptr, colidx, dinv, hbB, hbS);
    k_conv_b<128, 64, 128, 2, ACT_RELU, false, true>
        <<<784, 512, shm(64, 128), stream>>>(hbB, Wt[6], hbS, bl4, hbA,
                                             nullptr, nullptr, nullptr);

    // ---- out = sigmoid(h4 @ W_lin + b_lin) * 1000 -> d_out ----
    k_conv_b<128, 32, 64, 2, ACT_SIGMOID1000, true, false>
        <<<784, 512, shm(32, 128), stream>>>(hbA, Wt[8], nullptr, b_lin,
                                             out_final, nullptr, nullptr,
                                             nullptr);
}

// Round 17
// 353.368 us; speedup vs baseline: 1.0874x; 1.0874x over previous
//
#include <hip/hip_runtime.h>
#include <hip/hip_bf16.h>

#define N_NODES 50000
#define E_EDGES 800000

using u16 = unsigned short;
typedef short bf8 __attribute__((ext_vector_type(8)));
typedef float f32x4 __attribute__((ext_vector_type(4)));

__device__ __forceinline__ float bf2f(u16 h) {
    union { unsigned u; float f; } v;
    v.u = ((unsigned)h) << 16;
    return v.f;
}
__device__ __forceinline__ u16 f2bf(float f) {
    union { float f; unsigned u; } v;
    v.f = f;
    unsigned r = v.u + 0x7FFF + ((v.u >> 16) & 1);
    return (u16)(r >> 16);
}

#define GLOAD_LDS16(gsrc, ldst)                                            \
    __builtin_amdgcn_global_load_lds(                                      \
        (const __attribute__((address_space(1))) void*)(gsrc),             \
        (__attribute__((address_space(3))) void*)(ldst), 16, 0, 0)

// ---------------- weight pack: W[k][n] fp32 -> MFMA B-fragment order bf16 ----
struct WtArgs {
    const float* src[9];
    u16* dst[9];
    int K[9];
    int N[9];
};

__global__ __launch_bounds__(256) void k_wpack(WtArgs a) {
    int wi = blockIdx.y;
    int K = a.K[wi], NC = a.N[wi];
    int KS = K / 32;
    int chunks = (NC / 16) * KS * 64;
    for (int c = blockIdx.x * 256 + threadIdx.x; c < chunks;
         c += gridDim.x * 256) {
        int l = c & 63;
        int rest = c >> 6;  // gni*KS + ks
        int ks = rest % KS, gni = rest / KS;
        int n = gni * 16 + (l & 15);
        int kb = ks * 32 + (l >> 4) * 8;
        u16 outv[8];
#pragma unroll
        for (int j = 0; j < 8; ++j)
            outv[j] = f2bf(a.src[wi][(size_t)(kb + j) * NC + n]);
        *(bf8*)&a.dst[wi][(size_t)c * 8] = *(bf8*)outv;
    }
}

// ---------------- prep: h0 = x/1000 - 0.5, fp32 -> bf16 ----------------
__global__ __launch_bounds__(256) void k_prep(const float* __restrict__ x,
                                              u16* __restrict__ h0) {
    int total = N_NODES * 128 / 4;
    for (int i = blockIdx.x * 256 + threadIdx.x; i < total;
         i += gridDim.x * 256) {
        float4 v = *(const float4*)(x + (size_t)i * 4);
        ushort4 o;
        o.x = f2bf(v.x * 0.001f - 0.5f);
        o.y = f2bf(v.y * 0.001f - 0.5f);
        o.z = f2bf(v.z * 0.001f - 0.5f);
        o.w = f2bf(v.w * 0.001f - 0.5f);
        *(ushort4*)(h0 + (size_t)i * 4) = o;
    }
}

// ---------------- degree count ----------------
__global__ void k_count(const int* __restrict__ dst, int* __restrict__ deg) {
    for (int i = blockIdx.x * blockDim.x + threadIdx.x; i < E_EDGES;
         i += gridDim.x * blockDim.x)
        atomicAdd(&deg[dst[i]], 1);
}

// ---------------- 3-phase parallel exclusive scan ----------------
#define SCAN_B 49  // ceil(50000/1024)

__global__ __launch_bounds__(1024) void k_scan1(const int* __restrict__ deg,
                                                int* __restrict__ bsum) {
    __shared__ int sm[1024];
    int i = blockIdx.x * 1024 + threadIdx.x;
    sm[threadIdx.x] = (i < N_NODES) ? deg[i] : 0;
    __syncthreads();
    for (int ofs = 512; ofs > 0; ofs >>= 1) {
        if (threadIdx.x < ofs) sm[threadIdx.x] += sm[threadIdx.x + ofs];
        __syncthreads();
    }
    if (threadIdx.x == 0) bsum[blockIdx.x] = sm[0];
}

__global__ void k_scan2(const int* __restrict__ bsum, int* __restrict__ bofs) {
    int l = threadIdx.x;  // one wave of 64
    int v = (l < SCAN_B) ? bsum[l] : 0;
    int orig = v;
    for (int d = 1; d < 64; d <<= 1) {
        int u = __shfl_up(v, d, 64);
        if (l >= d) v += u;
    }
    if (l < SCAN_B) bofs[l] = v - orig;  // exclusive
}

__global__ __launch_bounds__(1024) void k_scan3(const int* __restrict__ deg,
                                                const int* __restrict__ bofs,
                                                int* __restrict__ rowptr,
                                                float* __restrict__ dinv) {
    __shared__ int sm[1024];
    int i = blockIdx.x * 1024 + threadIdx.x;
    int d = (i < N_NODES) ? deg[i] : 0;
    sm[threadIdx.x] = d;
    __syncthreads();
    for (int ofs = 1; ofs < 1024; ofs <<= 1) {
        int u = (threadIdx.x >= (unsigned)ofs) ? sm[threadIdx.x - ofs] : 0;
        __syncthreads();
        sm[threadIdx.x] += u;
        __syncthreads();
    }
    if (i < N_NODES) {
        int incl = sm[threadIdx.x] + bofs[blockIdx.x];
        rowptr[i] = incl - d;
        dinv[i] = 1.0f / fmaxf((float)d, 1.0f);
        if (i == N_NODES - 1) rowptr[N_NODES] = incl;
    }
}

// ---------------- CSR fill ----------------
__global__ void k_fill(const int* __restrict__ src, const int* __restrict__ dst,
                       const int* __restrict__ rowptr, int* __restrict__ cursor,
                       int* __restrict__ colidx) {
    for (int i = blockIdx.x * blockDim.x + threadIdx.x; i < E_EDGES;
         i += gridDim.x * blockDim.x) {
        int d = dst[i];
        int pos = rowptr[d] + atomicAdd(&cursor[d], 1);
        colidx[pos] = src[i];
    }
}

// ---------------- neighbor-mean aggregation: 1 wave/node ---------------------
// Index preload: lanes 0..63 load colidx[beg+lane] in ONE coalesced vector
// load; the edge loop gets src indices via __shfl (register bpermute) so the
// only in-loop memory ops are the independent gather loads (8 edges in flight
// per wave). Kills the colidx->gather serial latency chain.
template <int D>
__global__ __launch_bounds__(256) void k_aggregate(
    const u16* __restrict__ h, const int* __restrict__ rowptr,
    const int* __restrict__ colidx, const float* __restrict__ dinv,
    u16* __restrict__ mean) {
    constexpr int VA = D / 16;  // bf16 per lane (8 or 16)
    int node = (int)((blockIdx.x * 256 + threadIdx.x) >> 6);
    int lane = threadIdx.x & 63;
    if (node >= N_NODES) return;
    int sub = lane >> 4, lr = lane & 15;
    int beg = rowptr[node], end = rowptr[node + 1];
    int deg = end - beg;
    float acc[VA] = {};
    for (int base = 0; base < deg; base += 64) {
        int nb = min(64, deg - base);
        int idx = 0;
        if (lane < nb) idx = colidx[beg + base + lane];
        int j = 0;
        // 8 edges in flight per wave (2 per 16-lane group)
        for (; j + 8 <= nb; j += 8) {
            int s0 = __shfl(idx, j + sub, 64);
            int s1 = __shfl(idx, j + 4 + sub, 64);
            const u16* p0 = h + (size_t)s0 * D + lr * VA;
            const u16* p1 = h + (size_t)s1 * D + lr * VA;
            bf8 r0 = *(const bf8*)p0;
            bf8 r1 = *(const bf8*)p1;
            if (VA == 16) {
                bf8 r0b = *(const bf8*)(p0 + 8);
                bf8 r1b = *(const bf8*)(p1 + 8);
#pragma unroll
                for (int q = 0; q < 8; ++q) {
                    acc[q] += bf2f((u16)r0[q]) + bf2f((u16)r1[q]);
                    acc[8 + q] += bf2f((u16)r0b[q]) + bf2f((u16)r1b[q]);
                }
            } else {
#pragma unroll
                for (int q = 0; q < 8; ++q)
                    acc[q] += bf2f((u16)r0[q]) + bf2f((u16)r1[q]);
            }
        }
        for (; j < nb; j += 4) {
            int e = j + sub;
            int ec = min(e, nb - 1);        // all lanes active at the shfl
            int s = __shfl(idx, ec, 64);
            if (e < nb) {
                const u16* row = h + (size_t)s * D + lr * VA;
                bf8 r0 = *(const bf8*)row;
#pragma unroll
                for (int q = 0; q < 8; ++q) acc[q] += bf2f((u16)r0[q]);
                if (VA == 16) {
                    bf8 r1 = *(const bf8*)(row + 8);
#pragma unroll
                    for (int q = 0; q < 8; ++q) acc[8 + q] += bf2f((u16)r1[q]);
                }
            }
        }
    }
#pragma unroll
    for (int j = 0; j < VA; ++j) {
        acc[j] += __shfl_xor(acc[j], 16);
        acc[j] += __shfl_xor(acc[j], 32);
    }
    if (sub == 0) {
        float inv = dinv[node];
        u16 outv[VA];
#pragma unroll
        for (int j = 0; j < VA; ++j) outv[j] = f2bf(acc[j] * inv);
        u16* o = mean + (size_t)node * D + lr * VA;
        *(bf8*)o = *(bf8*)&outv[0];
        if (VA == 16) *(bf8*)(o + 8) = *(bf8*)&outv[8];
    }
}

// ---------------- bf16 MFMA GEMM: single-pass concatenated-K -----------------
// A = [A1 | A2] (mean | h), W = [Wp1 ; Wp2] both staged up-front via
// global_load_lds (async, wave-uniform LDS base + lane*16B). ONE barrier, then
// an uninterrupted K-loop with rolling 1-deep A prefetch. Packed-fragment LDS
// -> conflict-free ds_read_b128. YS-way N-split; bijective XCD chunking; eps
// prefetched at start (VAE).
enum { ACT_NONE = 0, ACT_SIN = 1, ACT_RELU = 2, ACT_SIGMOID1000 = 3, ACT_VAE = 4 };

template <int K, int NCB, int NC, int YS, int ACT, bool OUT_F32, bool TWO_PASS>
__global__ __launch_bounds__(512) void k_gemm(
    const u16* __restrict__ A1, const u16* __restrict__ Wp1,
    const u16* __restrict__ A2, const u16* __restrict__ Wp2,
    const float* __restrict__ bias, void* __restrict__ Cout,
    float* __restrict__ out_mean, float* __restrict__ out_lv,
    const float* __restrict__ eps) {
    constexpr int M = N_NODES;
    constexpr int NG = NCB / 16;           // col groups per block
    constexpr int KS1 = K / 32;            // k-steps per operand
    constexpr int KST = TWO_PASS ? 2 * KS1 : KS1;
    constexpr int CH1 = NG * KS1 * 64;     // 16B chunks per W operand tile
    constexpr int GX = (M / 16 + 7) / 8;   // 391 (128 rows/block)
    constexpr int NWG = ((GX * YS + 7) / 8) * 8;
    constexpr int CPX = NWG / 8;
    extern __shared__ char smem[];
    u16* Bs = (u16*)smem;

    const int bid = blockIdx.x;
    const int wid = (bid & 7) * CPX + (bid >> 3);  // bijective XCD chunking
    const int x = wid / YS;
    const int y = wid % YS;
    if (x >= GX) return;

    const int t = threadIdx.x;
    const int lane = t & 63;
    const int wave = t >> 6;
    const int lr = lane & 15;
    const int sub = lane >> 4;
    const int row0 = (x * 8 + wave) * 16;
    const int arow = row0 + lr;
    const bool rowOK = arow < M;

    // local col-group -> global col-group (VAE pairs mean c with log_var c+128)
    auto mapGroup = [&](int ni) {
        if (ACT == ACT_VAE)
            return ni < NG / 2 ? y * (NG / 2) + ni
                               : (NC / 32) + y * (NG / 2) + (ni - NG / 2);
        return y * NG + ni;
    };

    // ---- async W staging: both operands, issued before anything else ----
    {
#pragma unroll
        for (int i = 0; i < CH1 / 512; ++i) {
            int c = t + i * 512;
            int ks = (c >> 6) % KS1;
            int ni = c / (64 * KS1);
            const u16* gsrc =
                Wp1 + (((size_t)mapGroup(ni) * KS1 + ks) * 64 + lane) * 8;
            u16* ldst = Bs + ((size_t)(i * 512 + wave * 64)) * 8;
            GLOAD_LDS16(gsrc, ldst);
        }
        if (TWO_PASS) {
#pragma unroll
            for (int i = 0; i < CH1 / 512; ++i) {
                int c = t + i * 512;
                int ks = (c >> 6) % KS1;
                int ni = c / (64 * KS1);
                const u16* gsrc =
                    Wp2 + (((size_t)mapGroup(ni) * KS1 + ks) * 64 + lane) * 8;
                u16* ldst = Bs + ((size_t)(CH1 + i * 512 + wave * 64)) * 8;
                GLOAD_LDS16(gsrc, ldst);
            }
        }
    }

    // ---- eps prefetch (VAE): hidden under staging ----
    float epsv[ACT == ACT_VAE ? 8 : 1];
    if (ACT == ACT_VAE) {
#pragma unroll
        for (int ni = 0; ni < NG / 2; ++ni) {
#pragma unroll
            for (int r = 0; r < 4; ++r) {
                int row = row0 + sub * 4 + r;
                int colm = y * (NCB / 2) + ni * 16 + lr;
                epsv[ni * 4 + r] =
                    (row < M) ? eps[(size_t)row * 128 + colm] : 0.f;
            }
        }
    }

    f32x4 acc[NG];
#pragma unroll
    for (int i = 0; i < NG; ++i) acc[i] = (f32x4){0.f, 0.f, 0.f, 0.f};

    auto aptr = [&](int ks) {
        return (ks < KS1 ? A1 + (size_t)arow * K + ks * 32
                         : A2 + (size_t)arow * K + (ks - KS1) * 32) +
               sub * 8;
    };

    __syncthreads();  // waits vmcnt(0): all W chunks landed in LDS

    // ---- uninterrupted K-loop, rolling 1-deep A prefetch ----
    bf8 acur = {0, 0, 0, 0, 0, 0, 0, 0};
    if (rowOK) acur = *(const bf8*)aptr(0);
#pragma unroll
    for (int ks = 0; ks < KST; ++ks) {
        bf8 anext = {0, 0, 0, 0, 0, 0, 0, 0};
        if (ks + 1 < KST && rowOK) anext = *(const bf8*)aptr(ks + 1);
#pragma unroll
        for (int ni = 0; ni < NG; ++ni) {
            size_t off = (ks < KS1)
                             ? (((size_t)ni * KS1 + ks) * 64)
                             : ((size_t)CH1 +
                                ((size_t)ni * KS1 + (ks - KS1)) * 64);
            bf8 b = *(const bf8*)&Bs[(off + lane) * 8];
            acc[ni] =
                __builtin_amdgcn_mfma_f32_16x16x32_bf16(acur, b, acc[ni], 0, 0, 0);
        }
        acur = anext;
    }

    if (ACT == ACT_VAE) {
        // ni < NG/2 = mean cols (global y*(NCB/2)+...), ni+NG/2 = log_var (+128)
#pragma unroll
        for (int ni = 0; ni < NG / 2; ++ni) {
            int colm = y * (NCB / 2) + ni * 16 + lr;
            float bm = bias[colm];
            float bl = bias[colm + 128];
#pragma unroll
            for (int r = 0; r < 4; ++r) {
                int row = row0 + sub * 4 + r;
                if (row >= M) continue;
                float mv = acc[ni][r] + bm;
                float lv = acc[ni + NG / 2][r] + bl;
                size_t o = (size_t)row * 128 + colm;
                out_mean[o] = mv;
                out_lv[o] = lv;
                ((u16*)Cout)[o] = f2bf(mv + __expf(lv) * epsv[ni * 4 + r]);
            }
        }
    } else {
#pragma unroll
        for (int ni = 0; ni < NG; ++ni) {
            int col = y * NCB + ni * 16 + lr;
            float bv = bias[col];
#pragma unroll
            for (int r = 0; r < 4; ++r) {
                int row = row0 + sub * 4 + r;
                if (row >= M) continue;
                float v = acc[ni][r] + bv;
                if (ACT == ACT_SIN) v = __sinf(v);
                else if (ACT == ACT_RELU) v = fmaxf(v, 0.f);
                else if (ACT == ACT_SIGMOID1000) v = 1000.f / (1.f + __expf(-v));
                if (OUT_F32)
                    ((float*)Cout)[(size_t)row * NC + col] = v;
                else
                    ((u16*)Cout)[(size_t)row * NC + col] = f2bf(v);
            }
        }
    }
}

extern "C" void kernel_launch(void* const* d_in, const int* in_sizes, int n_in,
                              void* d_out, int out_size, void* d_ws,
                              size_t ws_size, hipStream_t stream) {
    const int N = N_NODES;
    const float* x = (const float*)d_in[0];
    const int* ei = (const int*)d_in[1];
    const float* eps = (const float*)d_in[2];
    const float* Wl1 = (const float*)d_in[3];
    const float* bl1 = (const float*)d_in[4];
    const float* Wr1 = (const float*)d_in[5];
    const float* Wl2 = (const float*)d_in[6];
    const float* bl2 = (const float*)d_in[7];
    const float* Wr2 = (const float*)d_in[8];
    const float* Wl3 = (const float*)d_in[9];
    const float* bl3 = (const float*)d_in[10];
    const float* Wr3 = (const float*)d_in[11];
    const float* Wl4 = (const float*)d_in[12];
    const float* bl4 = (const float*)d_in[13];
    const float* Wr4 = (const float*)d_in[14];
    const float* W_lin = (const float*)d_in[15];
    const float* b_lin = (const float*)d_in[16];

    const int* src = ei;
    const int* dst = ei + E_EDGES;

    char* w = (char*)d_ws;
    auto alloc = [&](size_t b) {
        void* p = (void*)w;
        w += (b + 255) & ~(size_t)255;
        return p;
    };
    int* deg = (int*)alloc((size_t)N * 4);
    int* rowptr = (int*)alloc((size_t)(N + 1) * 4);
    int* cursor = (int*)alloc((size_t)N * 4);
    int* colidx = (int*)alloc((size_t)E_EDGES * 4);
    float* dinv = (float*)alloc((size_t)N * 4);
    int* bsum = (int*)alloc(64 * 4);
    int* bofs = (int*)alloc(64 * 4);
    u16* hbA = (u16*)alloc((size_t)N * 256 * 2);
    u16* hbB = (u16*)alloc((size_t)N * 256 * 2);
    u16* hbC = (u16*)alloc((size_t)N * 256 * 2);
    static const int wK[9] = {128, 128, 256, 256, 128, 128, 128, 128, 128};
    static const int wN[9] = {256, 256, 256, 256, 128, 128, 128, 128, 64};
    u16* Wt[9];
    for (int i = 0; i < 9; ++i) Wt[i] = (u16*)alloc((size_t)wK[i] * wN[i] * 2);

    float* out_final = (float*)d_out;              // N x 64
    float* out_mean = out_final + (size_t)N * 64;  // N x 128
    float* out_lv = out_mean + (size_t)N * 128;    // N x 128

    hipMemsetAsync(deg, 0, (size_t)N * 4, stream);
    hipMemsetAsync(cursor, 0, (size_t)N * 4, stream);

    WtArgs wa;
    const float* wsrc[9] = {Wl1, Wr1, Wl2, Wr2, Wl3, Wr3, Wl4, Wr4, W_lin};
    for (int i = 0; i < 9; ++i) {
        wa.src[i] = wsrc[i];
        wa.dst[i] = Wt[i];
        wa.K[i] = wK[i];
        wa.N[i] = wN[i];
    }
    k_wpack<<<dim3(32, 9), 256, 0, stream>>>(wa);

    k_prep<<<2048, 256, 0, stream>>>(x, hbA);
    k_count<<<3125, 256, 0, stream>>>(dst, deg);
    k_scan1<<<SCAN_B, 1024, 0, stream>>>(deg, bsum);
    k_scan2<<<1, 64, 0, stream>>>(bsum, bofs);
    k_scan3<<<SCAN_B, 1024, 0, stream>>>(deg, bofs, rowptr, dinv);
    k_fill<<<3125, 256, 0, stream>>>(src, dst, rowptr, cursor, colidx);

    const int aggBlocks = (N * 64 + 255) / 256;  // one wave per node
    auto nwg = [](int YS) { return ((391 * YS + 7) / 8) * 8; };
    auto shm = [](int NCB, int Ktot) { return (size_t)NCB * Ktot * 2; };

    // conv1: h1 = sin(mean(h0)@Wl1 + bl1 + h0@Wr1)  (N x 256) -> hbC
    k_aggregate<128><<<aggBlocks, 256, 0, stream>>>(hbA, rowptr, colidx, dinv,
                                                    hbB);
    k_gemm<128, 64, 256, 4, ACT_SIN, false, true>
        <<<nwg(4), 512, shm(64, 256), stream>>>(hbB, Wt[0], hbA, Wt[1], bl1,
                                                hbC, nullptr, nullptr, nullptr);

    // conv2 + fused reparam: writes out_mean, out_lv, z(bf16)->hbA
    k_aggregate<256><<<aggBlocks, 256, 0, stream>>>(hbC, rowptr, colidx, dinv,
                                                    hbB);
    k_gemm<256, 64, 256, 4, ACT_VAE, false, true>
        <<<nwg(4), 512, shm(64, 512), stream>>>(hbB, Wt[2], hbC, Wt[3], bl2,
                                                hbA, out_mean, out_lv, eps);

    // conv3: h3 = relu(mean(z)@Wl3 + bl3 + z@Wr3)   (N x 128) -> hbC
    k_aggregate<128><<<aggBlocks, 256, 0, stream>>>(hbA, rowptr, colidx, dinv,
                                                    hbB);
    k_gemm<128, 64, 128, 2, ACT_RELU, false, true>
        <<<nwg(2), 512, shm(64, 256), stream>>>(hbB, Wt[4], hbA, Wt[5], bl3,
                                                hbC, nullptr, nullptr, nullptr);

    // conv4: h4 = relu(mean(h3)@Wl4 + bl4 + h3@Wr4) (N x 128) -> hbA
    k_aggregate<128><<<aggBlocks, 256, 0, stream>>>(hbC, rowptr, colidx, dinv,
                                                    hbB);
    k_gemm<128, 64, 128, 2, ACT_RELU, false, true>
        <<<nwg(2), 512, shm(64, 256), stream>>>(hbB, Wt[6], hbC, Wt[7], bl4,
                                                hbA, nullptr, nullptr, nullptr);

    // out = sigmoid(h4 @ W_lin + b_lin) * 1000      (N x 64, fp32) -> d_out
    k_gemm<128, 32, 64, 2, ACT_SIGMOID1000, true, false>
        <<<nwg(2), 512, shm(32, 128), stream>>>(hbA, Wt[8], nullptr, nullptr,
                                                b_lin, out_final, nullptr,
                                                nullptr, nullptr);
}

// Round 18
// 319.018 us; speedup vs baseline: 1.2045x; 1.1077x over previous
//
#include <hip/hip_runtime.h>
#include <hip/hip_bf16.h>

#define N_NODES 50000
#define E_EDGES 800000

using u16 = unsigned short;
typedef short bf8 __attribute__((ext_vector_type(8)));
typedef float f32x4 __attribute__((ext_vector_type(4)));

__device__ __forceinline__ float bf2f(u16 h) {
    union { unsigned u; float f; } v;
    v.u = ((unsigned)h) << 16;
    return v.f;
}
__device__ __forceinline__ u16 f2bf(float f) {
    union { float f; unsigned u; } v;
    v.f = f;
    unsigned r = v.u + 0x7FFF + ((v.u >> 16) & 1);
    return (u16)(r >> 16);
}

#define GLOAD_LDS16(gsrc, ldst)                                            \
    __builtin_amdgcn_global_load_lds(                                      \
        (const __attribute__((address_space(1))) void*)(gsrc),             \
        (__attribute__((address_space(3))) void*)(ldst), 16, 0, 0)

// ---------------- weight pack: W[k][n] fp32 -> MFMA B-fragment order bf16 ----
struct WtArgs {
    const float* src[9];
    u16* dst[9];
    int K[9];
    int N[9];
};

__global__ __launch_bounds__(256) void k_wpack(WtArgs a) {
    int wi = blockIdx.y;
    int K = a.K[wi], NC = a.N[wi];
    int KS = K / 32;
    int chunks = (NC / 16) * KS * 64;
    for (int c = blockIdx.x * 256 + threadIdx.x; c < chunks;
         c += gridDim.x * 256) {
        int l = c & 63;
        int rest = c >> 6;  // gni*KS + ks
        int ks = rest % KS, gni = rest / KS;
        int n = gni * 16 + (l & 15);
        int kb = ks * 32 + (l >> 4) * 8;
        u16 outv[8];
#pragma unroll
        for (int j = 0; j < 8; ++j)
            outv[j] = f2bf(a.src[wi][(size_t)(kb + j) * NC + n]);
        *(bf8*)&a.dst[wi][(size_t)c * 8] = *(bf8*)outv;
    }
}

// ---------------- prep: h0 = x/1000 - 0.5, fp32 -> bf16 ----------------
__global__ __launch_bounds__(256) void k_prep(const float* __restrict__ x,
                                              u16* __restrict__ h0) {
    int total = N_NODES * 128 / 4;
    for (int i = blockIdx.x * 256 + threadIdx.x; i < total;
         i += gridDim.x * 256) {
        float4 v = *(const float4*)(x + (size_t)i * 4);
        ushort4 o;
        o.x = f2bf(v.x * 0.001f - 0.5f);
        o.y = f2bf(v.y * 0.001f - 0.5f);
        o.z = f2bf(v.z * 0.001f - 0.5f);
        o.w = f2bf(v.w * 0.001f - 0.5f);
        *(ushort4*)(h0 + (size_t)i * 4) = o;
    }
}

// ---------------- degree count + per-edge rank (atomic return) ----------------
__global__ void k_count(const int* __restrict__ dst, int* __restrict__ deg,
                        int* __restrict__ rank) {
    for (int i = blockIdx.x * blockDim.x + threadIdx.x; i < E_EDGES;
         i += gridDim.x * blockDim.x)
        rank[i] = atomicAdd(&deg[dst[i]], 1);
}

// ---------------- 3-phase parallel exclusive scan ----------------
#define SCAN_B 49  // ceil(50000/1024)

__global__ __launch_bounds__(1024) void k_scan1(const int* __restrict__ deg,
                                                int* __restrict__ bsum) {
    __shared__ int sm[1024];
    int i = blockIdx.x * 1024 + threadIdx.x;
    sm[threadIdx.x] = (i < N_NODES) ? deg[i] : 0;
    __syncthreads();
    for (int ofs = 512; ofs > 0; ofs >>= 1) {
        if (threadIdx.x < ofs) sm[threadIdx.x] += sm[threadIdx.x + ofs];
        __syncthreads();
    }
    if (threadIdx.x == 0) bsum[blockIdx.x] = sm[0];
}

__global__ void k_scan2(const int* __restrict__ bsum, int* __restrict__ bofs) {
    int l = threadIdx.x;  // one wave of 64
    int v = (l < SCAN_B) ? bsum[l] : 0;
    int orig = v;
    for (int d = 1; d < 64; d <<= 1) {
        int u = __shfl_up(v, d, 64);
        if (l >= d) v += u;
    }
    if (l < SCAN_B) bofs[l] = v - orig;  // exclusive
}

__global__ __launch_bounds__(1024) void k_scan3(const int* __restrict__ deg,
                                                const int* __restrict__ bofs,
                                                int* __restrict__ rowptr,
                                                float* __restrict__ dinv) {
    __shared__ int sm[1024];
    int i = blockIdx.x * 1024 + threadIdx.x;
    int d = (i < N_NODES) ? deg[i] : 0;
    sm[threadIdx.x] = d;
    __syncthreads();
    for (int ofs = 1; ofs < 1024; ofs <<= 1) {
        int u = (threadIdx.x >= (unsigned)ofs) ? sm[threadIdx.x - ofs] : 0;
        __syncthreads();
        sm[threadIdx.x] += u;
        __syncthreads();
    }
    if (i < N_NODES) {
        int incl = sm[threadIdx.x] + bofs[blockIdx.x];
        rowptr[i] = incl - d;
        dinv[i] = 1.0f / fmaxf((float)d, 1.0f);
        if (i == N_NODES - 1) rowptr[N_NODES] = incl;
    }
}

// ---------------- CSR fill: NO atomics (rank precomputed in k_count) ---------
__global__ void k_fill(const int* __restrict__ src, const int* __restrict__ dst,
                       const int* __restrict__ rowptr,
                       const int* __restrict__ rank,
                       int* __restrict__ colidx) {
    for (int i = blockIdx.x * blockDim.x + threadIdx.x; i < E_EDGES;
         i += gridDim.x * blockDim.x) {
        int d = dst[i];
        colidx[rowptr[d] + rank[i]] = src[i];
    }
}

// ---------------- neighbor-mean aggregation: 1 wave/node ---------------------
// Index preload: lanes 0..63 load colidx[beg+lane] in ONE coalesced vector
// load; the edge loop gets src indices via __shfl so the only in-loop memory
// ops are the independent gather loads (8 edges in flight per wave).
template <int D>
__global__ __launch_bounds__(256) void k_aggregate(
    const u16* __restrict__ h, const int* __restrict__ rowptr,
    const int* __restrict__ colidx, const float* __restrict__ dinv,
    u16* __restrict__ mean) {
    constexpr int VA = D / 16;  // bf16 per lane (8 or 16)
    int node = (int)((blockIdx.x * 256 + threadIdx.x) >> 6);
    int lane = threadIdx.x & 63;
    if (node >= N_NODES) return;
    int sub = lane >> 4, lr = lane & 15;
    int beg = rowptr[node], end = rowptr[node + 1];
    int deg = end - beg;
    float acc[VA] = {};
    for (int base = 0; base < deg; base += 64) {
        int nb = min(64, deg - base);
        int idx = 0;
        if (lane < nb) idx = colidx[beg + base + lane];
        int j = 0;
        for (; j + 8 <= nb; j += 8) {
            int s0 = __shfl(idx, j + sub, 64);
            int s1 = __shfl(idx, j + 4 + sub, 64);
            const u16* p0 = h + (size_t)s0 * D + lr * VA;
            const u16* p1 = h + (size_t)s1 * D + lr * VA;
            bf8 r0 = *(const bf8*)p0;
            bf8 r1 = *(const bf8*)p1;
            if (VA == 16) {
                bf8 r0b = *(const bf8*)(p0 + 8);
                bf8 r1b = *(const bf8*)(p1 + 8);
#pragma unroll
                for (int q = 0; q < 8; ++q) {
                    acc[q] += bf2f((u16)r0[q]) + bf2f((u16)r1[q]);
                    acc[8 + q] += bf2f((u16)r0b[q]) + bf2f((u16)r1b[q]);
                }
            } else {
#pragma unroll
                for (int q = 0; q < 8; ++q)
                    acc[q] += bf2f((u16)r0[q]) + bf2f((u16)r1[q]);
            }
        }
        for (; j < nb; j += 4) {
            int e = j + sub;
            int ec = min(e, nb - 1);  // all lanes active at the shfl
            int s = __shfl(idx, ec, 64);
            if (e < nb) {
                const u16* row = h + (size_t)s * D + lr * VA;
                bf8 r0 = *(const bf8*)row;
#pragma unroll
                for (int q = 0; q < 8; ++q) acc[q] += bf2f((u16)r0[q]);
                if (VA == 16) {
                    bf8 r1 = *(const bf8*)(row + 8);
#pragma unroll
                    for (int q = 0; q < 8; ++q) acc[8 + q] += bf2f((u16)r1[q]);
                }
            }
        }
    }
#pragma unroll
    for (int j = 0; j < VA; ++j) {
        acc[j] += __shfl_xor(acc[j], 16);
        acc[j] += __shfl_xor(acc[j], 32);
    }
    if (sub == 0) {
        float inv = dinv[node];
        u16 outv[VA];
#pragma unroll
        for (int j = 0; j < VA; ++j) outv[j] = f2bf(acc[j] * inv);
        u16* o = mean + (size_t)node * D + lr * VA;
        *(bf8*)o = *(bf8*)&outv[0];
        if (VA == 16) *(bf8*)(o + 8) = *(bf8*)&outv[8];
    }
}

// ---------------- bf16 MFMA GEMM: single-pass concatenated-K -----------------
enum { ACT_NONE = 0, ACT_SIN = 1, ACT_RELU = 2, ACT_SIGMOID1000 = 3, ACT_VAE = 4 };

template <int K, int NCB, int NC, int YS, int ACT, bool OUT_F32, bool TWO_PASS>
__global__ __launch_bounds__(512) void k_gemm(
    const u16* __restrict__ A1, const u16* __restrict__ Wp1,
    const u16* __restrict__ A2, const u16* __restrict__ Wp2,
    const float* __restrict__ bias, void* __restrict__ Cout,
    float* __restrict__ out_mean, float* __restrict__ out_lv,
    const float* __restrict__ eps) {
    constexpr int M = N_NODES;
    constexpr int NG = NCB / 16;           // col groups per block
    constexpr int KS1 = K / 32;            // k-steps per operand
    constexpr int KST = TWO_PASS ? 2 * KS1 : KS1;
    constexpr int CH1 = NG * KS1 * 64;     // 16B chunks per W operand tile
    constexpr int GX = (M / 16 + 7) / 8;   // 391 (128 rows/block)
    constexpr int NWG = ((GX * YS + 7) / 8) * 8;
    constexpr int CPX = NWG / 8;
    extern __shared__ char smem[];
    u16* Bs = (u16*)smem;

    const int bid = blockIdx.x;
    const int wid = (bid & 7) * CPX + (bid >> 3);  // bijective XCD chunking
    const int x = wid / YS;
    const int y = wid % YS;
    if (x >= GX) return;

    const int t = threadIdx.x;
    const int lane = t & 63;
    const int wave = t >> 6;
    const int lr = lane & 15;
    const int sub = lane >> 4;
    const int row0 = (x * 8 + wave) * 16;
    const int arow = row0 + lr;
    const bool rowOK = arow < M;

    auto mapGroup = [&](int ni) {
        if (ACT == ACT_VAE)
            return ni < NG / 2 ? y * (NG / 2) + ni
                               : (NC / 32) + y * (NG / 2) + (ni - NG / 2);
        return y * NG + ni;
    };

    // ---- async W staging: both operands, issued before anything else ----
    {
#pragma unroll
        for (int i = 0; i < CH1 / 512; ++i) {
            int c = t + i * 512;
            int ks = (c >> 6) % KS1;
            int ni = c / (64 * KS1);
            const u16* gsrc =
                Wp1 + (((size_t)mapGroup(ni) * KS1 + ks) * 64 + lane) * 8;
            u16* ldst = Bs + ((size_t)(i * 512 + wave * 64)) * 8;
            GLOAD_LDS16(gsrc, ldst);
        }
        if (TWO_PASS) {
#pragma unroll
            for (int i = 0; i < CH1 / 512; ++i) {
                int c = t + i * 512;
                int ks = (c >> 6) % KS1;
                int ni = c / (64 * KS1);
                const u16* gsrc =
                    Wp2 + (((size_t)mapGroup(ni) * KS1 + ks) * 64 + lane) * 8;
                u16* ldst = Bs + ((size_t)(CH1 + i * 512 + wave * 64)) * 8;
                GLOAD_LDS16(gsrc, ldst);
            }
        }
    }

    // ---- eps prefetch (VAE): hidden under staging ----
    float epsv[ACT == ACT_VAE ? 8 : 1];
    if (ACT == ACT_VAE) {
#pragma unroll
        for (int ni = 0; ni < NG / 2; ++ni) {
#pragma unroll
            for (int r = 0; r < 4; ++r) {
                int row = row0 + sub * 4 + r;
                int colm = y * (NCB / 2) + ni * 16 + lr;
                epsv[ni * 4 + r] =
                    (row < M) ? eps[(size_t)row * 128 + colm] : 0.f;
            }
        }
    }

    f32x4 acc[NG];
#pragma unroll
    for (int i = 0; i < NG; ++i) acc[i] = (f32x4){0.f, 0.f, 0.f, 0.f};

    auto aptr = [&](int ks) {
        return (ks < KS1 ? A1 + (size_t)arow * K + ks * 32
                         : A2 + (size_t)arow * K + (ks - KS1) * 32) +
               sub * 8;
    };

    __syncthreads();  // waits vmcnt(0): all W chunks landed in LDS

    // ---- uninterrupted K-loop, rolling 1-deep A prefetch ----
    bf8 acur = {0, 0, 0, 0, 0, 0, 0, 0};
    if (rowOK) acur = *(const bf8*)aptr(0);
#pragma unroll
    for (int ks = 0; ks < KST; ++ks) {
        bf8 anext = {0, 0, 0, 0, 0, 0, 0, 0};
        if (ks + 1 < KST && rowOK) anext = *(const bf8*)aptr(ks + 1);
#pragma unroll
        for (int ni = 0; ni < NG; ++ni) {
            size_t off = (ks < KS1)
                             ? (((size_t)ni * KS1 + ks) * 64)
                             : ((size_t)CH1 +
                                ((size_t)ni * KS1 + (ks - KS1)) * 64);
            bf8 b = *(const bf8*)&Bs[(off + lane) * 8];
            acc[ni] =
                __builtin_amdgcn_mfma_f32_16x16x32_bf16(acur, b, acc[ni], 0, 0, 0);
        }
        acur = anext;
    }

    if (ACT == ACT_VAE) {
#pragma unroll
        for (int ni = 0; ni < NG / 2; ++ni) {
            int colm = y * (NCB / 2) + ni * 16 + lr;
            float bm = bias[colm];
            float bl = bias[colm + 128];
#pragma unroll
            for (int r = 0; r < 4; ++r) {
                int row = row0 + sub * 4 + r;
                if (row >= M) continue;
                float mv = acc[ni][r] + bm;
                float lv = acc[ni + NG / 2][r] + bl;
                size_t o = (size_t)row * 128 + colm;
                out_mean[o] = mv;
                out_lv[o] = lv;
                ((u16*)Cout)[o] = f2bf(mv + __expf(lv) * epsv[ni * 4 + r]);
            }
        }
    } else {
#pragma unroll
        for (int ni = 0; ni < NG; ++ni) {
            int col = y * NCB + ni * 16 + lr;
            float bv = bias[col];
#pragma unroll
            for (int r = 0; r < 4; ++r) {
                int row = row0 + sub * 4 + r;
                if (row >= M) continue;
                float v = acc[ni][r] + bv;
                if (ACT == ACT_SIN) v = __sinf(v);
                else if (ACT == ACT_RELU) v = fmaxf(v, 0.f);
                else if (ACT == ACT_SIGMOID1000) v = 1000.f / (1.f + __expf(-v));
                if (OUT_F32)
                    ((float*)Cout)[(size_t)row * NC + col] = v;
                else
                    ((u16*)Cout)[(size_t)row * NC + col] = f2bf(v);
            }
        }
    }
}

extern "C" void kernel_launch(void* const* d_in, const int* in_sizes, int n_in,
                              void* d_out, int out_size, void* d_ws,
                              size_t ws_size, hipStream_t stream) {
    const int N = N_NODES;
    const float* x = (const float*)d_in[0];
    const int* ei = (const int*)d_in[1];
    const float* eps = (const float*)d_in[2];
    const float* Wl1 = (const float*)d_in[3];
    const float* bl1 = (const float*)d_in[4];
    const float* Wr1 = (const float*)d_in[5];
    const float* Wl2 = (const float*)d_in[6];
    const float* bl2 = (const float*)d_in[7];
    const float* Wr2 = (const float*)d_in[8];
    const float* Wl3 = (const float*)d_in[9];
    const float* bl3 = (const float*)d_in[10];
    const float* Wr3 = (const float*)d_in[11];
    const float* Wl4 = (const float*)d_in[12];
    const float* bl4 = (const float*)d_in[13];
    const float* Wr4 = (const float*)d_in[14];
    const float* W_lin = (const float*)d_in[15];
    const float* b_lin = (const float*)d_in[16];

    const int* src = ei;
    const int* dst = ei + E_EDGES;

    char* w = (char*)d_ws;
    auto alloc = [&](size_t b) {
        void* p = (void*)w;
        w += (b + 255) & ~(size_t)255;
        return p;
    };
    int* deg = (int*)alloc((size_t)N * 4);
    int* rowptr = (int*)alloc((size_t)(N + 1) * 4);
    int* rank = (int*)alloc((size_t)E_EDGES * 4);
    int* colidx = (int*)alloc((size_t)E_EDGES * 4);
    float* dinv = (float*)alloc((size_t)N * 4);
    int* bsum = (int*)alloc(64 * 4);
    int* bofs = (int*)alloc(64 * 4);
    u16* hbA = (u16*)alloc((size_t)N * 256 * 2);
    u16* hbB = (u16*)alloc((size_t)N * 256 * 2);
    u16* hbC = (u16*)alloc((size_t)N * 256 * 2);
    static const int wK[9] = {128, 128, 256, 256, 128, 128, 128, 128, 128};
    static const int wN[9] = {256, 256, 256, 256, 128, 128, 128, 128, 64};
    u16* Wt[9];
    for (int i = 0; i < 9; ++i) Wt[i] = (u16*)alloc((size_t)wK[i] * wN[i] * 2);

    float* out_final = (float*)d_out;              // N x 64
    float* out_mean = out_final + (size_t)N * 64;  // N x 128
    float* out_lv = out_mean + (size_t)N * 128;    // N x 128

    hipMemsetAsync(deg, 0, (size_t)N * 4, stream);

    WtArgs wa;
    const float* wsrc[9] = {Wl1, Wr1, Wl2, Wr2, Wl3, Wr3, Wl4, Wr4, W_lin};
    for (int i = 0; i < 9; ++i) {
        wa.src[i] = wsrc[i];
        wa.dst[i] = Wt[i];
        wa.K[i] = wK[i];
        wa.N[i] = wN[i];
    }
    k_wpack<<<dim3(32, 9), 256, 0, stream>>>(wa);

    k_prep<<<2048, 256, 0, stream>>>(x, hbA);
    k_count<<<3125, 256, 0, stream>>>(dst, deg, rank);
    k_scan1<<<SCAN_B, 1024, 0, stream>>>(deg, bsum);
    k_scan2<<<1, 64, 0, stream>>>(bsum, bofs);
    k_scan3<<<SCAN_B, 1024, 0, stream>>>(deg, bofs, rowptr, dinv);
    k_fill<<<3125, 256, 0, stream>>>(src, dst, rowptr, rank, colidx);

    const int aggBlocks = (N * 64 + 255) / 256;  // one wave per node
    auto nwg = [](int YS) { return ((391 * YS + 7) / 8) * 8; };
    auto shm = [](int NCB, int Ktot) { return (size_t)NCB * Ktot * 2; };

    // conv1: h1 = sin(mean(h0)@Wl1 + bl1 + h0@Wr1)  (N x 256) -> hbC
    k_aggregate<128><<<aggBlocks, 256, 0, stream>>>(hbA, rowptr, colidx, dinv,
                                                    hbB);
    k_gemm<128, 64, 256, 4, ACT_SIN, false, true>
        <<<nwg(4), 512, shm(64, 256), stream>>>(hbB, Wt[0], hbA, Wt[1], bl1,
                                                hbC, nullptr, nullptr, nullptr);

    // conv2 + fused reparam: writes out_mean, out_lv, z(bf16)->hbA
    k_aggregate<256><<<aggBlocks, 256, 0, stream>>>(hbC, rowptr, colidx, dinv,
                                                    hbB);
    k_gemm<256, 64, 256, 4, ACT_VAE, false, true>
        <<<nwg(4), 512, shm(64, 512), stream>>>(hbB, Wt[2], hbC, Wt[3], bl2,
                                                hbA, out_mean, out_lv, eps);

    // conv3: h3 = relu(mean(z)@Wl3 + bl3 + z@Wr3)   (N x 128) -> hbC
    k_aggregate<128><<<aggBlocks, 256, 0, stream>>>(hbA, rowptr, colidx, dinv,
                                                    hbB);
    k_gemm<128, 64, 128, 2, ACT_RELU, false, true>
        <<<nwg(2), 512, shm(64, 256), stream>>>(hbB, Wt[4], hbA, Wt[5], bl3,
                                                hbC, nullptr, nullptr, nullptr);

    // conv4: h4 = relu(mean(h3)@Wl4 + bl4 + h3@Wr4) (N x 128) -> hbA
    k_aggregate<128><<<aggBlocks, 256, 0, stream>>>(hbC, rowptr, colidx, dinv,
                                                    hbB);
    k_gemm<128, 64, 128, 2, ACT_RELU, false, true>
        <<<nwg(2), 512, shm(64, 256), stream>>>(hbB, Wt[6], hbC, Wt[7], bl4,
                                                hbA, nullptr, nullptr, nullptr);

    // out = sigmoid(h4 @ W_lin + b_lin) * 1000      (N x 64, fp32) -> d_out
    k_gemm<128, 32, 64, 2, ACT_SIGMOID1000, true, false>
        <<<nwg(2), 512, shm(32, 128), stream>>>(hbA, Wt[8], nullptr, nullptr,
                                                b_lin, out_final, nullptr,
                                                nullptr, nullptr);
}